// Round 8
// baseline (179.400 us; speedup 1.0000x reference)
//
#include <hip/hip_runtime.h>

// Unfold (im2col): x[8,64,224,224] f32, 3x3 kernel, pad=1, stride=1, dil=1
// out[b, c*9 + k, oh*224 + ow] = x[b, c, oh+ki-1, ow+kj-1] (0 outside), k = ki*3+kj
//
// Paired-quad x4: lane l of wave w owns image-quads w*256+l+{0,64,128,192}.
// Every store instruction remains a 1KB-aligned fully-contiguous 1KB burst
// (8 complete 128B lines) => nontemporal stores safe (R2: nt + partial lines
// amplifies). nt bypasses L2/LLC for the 925MB write-once stream. x4 batching
// lengthens load/store phases (fewer HBM r/w turnarounds) and halves index
// math per byte vs R6.

typedef float v4f __attribute__((ext_vector_type(4)));

constexpr int B = 8, C = 64, H = 224, W = 224;
constexpr int L  = H * W;          // 50176
constexpr int L4 = L / 4;          // 12544 quads per image; 12544 % 256 == 0
constexpr int W4 = W / 4;          // 56 quads per row
constexpr int CC = B * C;          // 512
constexpr unsigned QTOT   = (unsigned)CC * (unsigned)L4;  // 6,422,528 quads
constexpr unsigned TOTALT = QTOT / 4u;                    // 1,605,632 threads

__global__ __launch_bounds__(256) void unfold_pq4_nt_kernel(const float* __restrict__ x,
                                                            float* __restrict__ out) {
    unsigned t    = blockIdx.x * 256u + threadIdx.x;
    unsigned wv   = t >> 6;
    unsigned lane = t & 63u;
    unsigned qA   = wv * 256u + lane;          // wave covers quads [wv*256, wv*256+255]

    unsigned cc   = qA / (unsigned)L4;         // magic-mul; 12544%256==0 -> no straddle
    unsigned remA = qA - cc * (unsigned)L4;

    const float* __restrict__ base = x + (size_t)cc * (size_t)L;

    v4f   q[4][3];
    float lf[4][3], rg[4][3];
    unsigned rem[4] = { remA, remA + 64u, remA + 128u, remA + 192u };

    // ---- load phase: 12 aligned float4 + 24 edge scalars ----
    #pragma unroll
    for (int s = 0; s < 4; ++s) {
        unsigned r  = rem[s];
        int oh  = (int)(r / (unsigned)W4);     // magic-mul
        int col = (int)(r - (unsigned)oh * (unsigned)W4) * 4;   // 0..220, 16B-aligned
        #pragma unroll
        for (int ki = 0; ki < 3; ++ki) {
            int ih = oh + ki - 1;
            if (ih >= 0 && ih < H) {
                const float* __restrict__ src = base + ih * W;
                q[s][ki]  = *reinterpret_cast<const v4f*>(src + col);  // packed across lanes
                lf[s][ki] = (col > 0)     ? src[col - 1] : 0.f;
                rg[s][ki] = (col < W - 4) ? src[col + 4] : 0.f;
            } else {
                q[s][ki] = (v4f)0.f; lf[s][ki] = 0.f; rg[s][ki] = 0.f;
            }
        }
    }

    // ---- store phase: 36 nontemporal float4 (full 1KB bursts per instr) ----
    v4f* __restrict__ o = reinterpret_cast<v4f*>(out);
    size_t cb = (size_t)cc * 9u * (size_t)L4;
    #pragma unroll
    for (int s = 0; s < 4; ++s) {
        size_t ob = cb + (size_t)rem[s];
        #pragma unroll
        for (int ki = 0; ki < 3; ++ki) {
            v4f qq = q[s][ki];
            v4f a = { lf[s][ki], qq[0], qq[1], qq[2] };   // kj = 0
            v4f c = { qq[1], qq[2], qq[3], rg[s][ki] };   // kj = 2
            __builtin_nontemporal_store(a,  o + ob + (size_t)(ki * 3 + 0) * (size_t)L4);
            __builtin_nontemporal_store(qq, o + ob + (size_t)(ki * 3 + 1) * (size_t)L4);
            __builtin_nontemporal_store(c,  o + ob + (size_t)(ki * 3 + 2) * (size_t)L4);
        }
    }
}

extern "C" void kernel_launch(void* const* d_in, const int* in_sizes, int n_in,
                              void* d_out, int out_size, void* d_ws, size_t ws_size,
                              hipStream_t stream) {
    const float* x = (const float*)d_in[0];
    float* out = (float*)d_out;
    unsigned blocks = TOTALT / 256u;  // 6,272
    unfold_pq4_nt_kernel<<<dim3(blocks), dim3(256), 0, stream>>>(x, out);
}

// Round 9
// 171.262 us; speedup vs baseline: 1.0475x; 1.0475x over previous
//
#include <hip/hip_runtime.h>

// Unfold (im2col): x[8,64,224,224] f32, 3x3 kernel, pad=1, stride=1, dil=1
// out[b, c*9 + k, oh*224 + ow] = x[b, c, oh+ki-1, ow+kj-1] (0 outside), k = ki*3+kj
//
// Paired-quad mapping (R4): lane l of wave w owns image-quads w*128+l and
// w*128+64+l => EVERY store instruction is a 1KB-aligned contiguous 1KB burst
// = 8 COMPLETE 128B lines. That makes nontemporal stores safe (R2's nt
// amplification came from partial-line instructions). nt bypasses L2 for the
// 925MB write-once stream, preserving L2 for the 3x-reused input.
// (R7 lesson: x4 coarsening regressed — VGPR-heavier threads + half the waves
//  lose more latency-hiding than turnaround batching gains. x2 is optimal.)

typedef float v4f __attribute__((ext_vector_type(4)));

constexpr int B = 8, C = 64, H = 224, W = 224;
constexpr int L  = H * W;          // 50176
constexpr int L4 = L / 4;          // 12544 quads per image; 12544 % 128 == 0
constexpr int W4 = W / 4;          // 56 quads per row
constexpr int CC = B * C;          // 512
constexpr unsigned QTOT   = (unsigned)CC * (unsigned)L4;  // 6,422,528 quads
constexpr unsigned TOTALT = QTOT / 2u;                    // 3,211,264 threads

__global__ __launch_bounds__(256) void unfold_pq_nt_kernel(const float* __restrict__ x,
                                                           float* __restrict__ out) {
    unsigned t    = blockIdx.x * 256u + threadIdx.x;
    unsigned wv   = t >> 6;
    unsigned lane = t & 63u;
    unsigned qA   = wv * 128u + lane;          // wave covers quads [wv*128, wv*128+127]

    unsigned cc   = qA / (unsigned)L4;         // magic-mul; wave never straddles cc
    unsigned remA = qA - cc * (unsigned)L4;

    const float* __restrict__ base = x + (size_t)cc * (size_t)L;

    v4f   q[2][3];
    float lf[2][3], rg[2][3];
    unsigned rem[2] = { remA, remA + 64u };    // remA + 64 < L4 guaranteed

    #pragma unroll
    for (int s = 0; s < 2; ++s) {
        unsigned r  = rem[s];
        int oh  = (int)(r / (unsigned)W4);     // magic-mul
        int col = (int)(r - (unsigned)oh * (unsigned)W4) * 4;   // 0..220, 16B-aligned
        #pragma unroll
        for (int ki = 0; ki < 3; ++ki) {
            int ih = oh + ki - 1;
            if (ih >= 0 && ih < H) {
                const float* __restrict__ src = base + ih * W;
                q[s][ki]  = *reinterpret_cast<const v4f*>(src + col);  // packed across lanes
                lf[s][ki] = (col > 0)     ? src[col - 1] : 0.f;
                rg[s][ki] = (col < W - 4) ? src[col + 4] : 0.f;
            } else {
                q[s][ki] = (v4f)0.f; lf[s][ki] = 0.f; rg[s][ki] = 0.f;
            }
        }
    }

    v4f* __restrict__ o = reinterpret_cast<v4f*>(out);
    size_t cb = (size_t)cc * 9u * (size_t)L4;
    #pragma unroll
    for (int s = 0; s < 2; ++s) {
        size_t ob = cb + (size_t)rem[s];
        #pragma unroll
        for (int ki = 0; ki < 3; ++ki) {
            v4f qq = q[s][ki];
            v4f a = { lf[s][ki], qq[0], qq[1], qq[2] };   // kj = 0
            v4f c = { qq[1], qq[2], qq[3], rg[s][ki] };   // kj = 2
            __builtin_nontemporal_store(a,  o + ob + (size_t)(ki * 3 + 0) * (size_t)L4);
            __builtin_nontemporal_store(qq, o + ob + (size_t)(ki * 3 + 1) * (size_t)L4);
            __builtin_nontemporal_store(c,  o + ob + (size_t)(ki * 3 + 2) * (size_t)L4);
        }
    }
}

extern "C" void kernel_launch(void* const* d_in, const int* in_sizes, int n_in,
                              void* d_out, int out_size, void* d_ws, size_t ws_size,
                              hipStream_t stream) {
    const float* x = (const float*)d_in[0];
    float* out = (float*)d_out;
    unsigned blocks = TOTALT / 256u;  // 12,544
    unfold_pq_nt_kernel<<<dim3(blocks), dim3(256), 0, stream>>>(x, out);
}